// Round 7
// baseline (293.839 us; speedup 1.0000x reference)
//
#include <hip/hip_runtime.h>
#include <math.h>

#define F 128
#define THREEF 384
#define N_RBF 20
#define CUTOFF 5.0f
#define CAP 64
#define TLDS_STRIDE 136   // shorts; 272 B row: 16B-aligned, ~2-way banks (free)

typedef __bf16 bf16x8 __attribute__((ext_vector_type(8)));
typedef float  f32x4  __attribute__((ext_vector_type(4)));

// ---------------------------------------------------------------------------
// Init (replaces the cnt-memset dispatch; no dependency on anything):
//   blocks [0,256)    : wcast — W1,W2 -> bf16 k-major
//   blocks [256,264)  : wrt — chunked transpose of Wr for gather
//   blocks [264,284)  : zero cnt (int4 stores)
// ---------------------------------------------------------------------------
__global__ __launch_bounds__(256) void init_kernel(
    const float* __restrict__ W1, const float* __restrict__ W2,
    const float* __restrict__ Wr,
    __bf16* __restrict__ W1T, __bf16* __restrict__ W2T,
    float* __restrict__ WrT, int* __restrict__ cnt, int N)
{
    const int tid = threadIdx.x;
    const int b   = blockIdx.x;

    if (b < 256) {                      // ---- wcast
        const int idx = b * 256 + tid;
        if (idx < 128 * 128) {
            const int n = idx >> 7, k = idx & 127;
            W1T[idx] = (__bf16)W1[k * F + n];
        }
        if (idx < 384 * 128) {
            const int n = idx >> 7, k = idx & 127;
            W2T[idx] = (__bf16)W2[k * THREEF + n];
        }
    } else if (b < 264) {               // ---- wrt
        const int idx = (b - 256) * 256 + tid;   // 0..2047
        if (idx >= 5 * 3 * 128) return;
        const int f  = idx & 127;
        const int c  = (idx >> 7) % 3;
        const int n4 = idx / (3 * 128);
        float4 v;
        v.x = Wr[(4 * n4 + 0) * THREEF + c * 128 + f];
        v.y = Wr[(4 * n4 + 1) * THREEF + c * 128 + f];
        v.z = Wr[(4 * n4 + 2) * THREEF + c * 128 + f];
        v.w = Wr[(4 * n4 + 3) * THREEF + c * 128 + f];
        ((float4*)WrT)[idx] = v;
    } else {                            // ---- zero cnt
        const int i = (b - 264) * 256 + tid;
        if (i < (N + 3) / 4) {
            int4 z; z.x = 0; z.y = 0; z.z = 0; z.w = 0;
            ((int4*)cnt)[i] = z;
        }
    }
}

// ---------------------------------------------------------------------------
// Work (build ∥ mlp as CONCURRENT block ranges — they are data-independent;
// both depend only on init_kernel's outputs):
//   blocks [0, EB)       : build — CSR slot via atomic, pack row written at
//                          (dst,slot): {s1, 2cos(x), fcut, ux, uy, uz, src, 0}
//   blocks [EB, EB+MB)   : mlp — phi = silu(h@W1+b1)@W2 + b2 via bf16 MFMA,
//                          3 planes [c][node][f]; 4 waves cooperate on the
//                          same 16 nodes (R6 occupancy fix, verified)
// With ~2500 blocks co-resident across 256 CUs, the shorter stage hides
// entirely under the longer one.
// ---------------------------------------------------------------------------
__global__ __launch_bounds__(256) void work_kernel(
    const float* __restrict__ d_ij, const float* __restrict__ unit_r,
    const int* __restrict__ nbrs,
    int* __restrict__ cnt, float* __restrict__ pack,
    const float* __restrict__ h,
    const __bf16* __restrict__ W1T, const float* __restrict__ b1,
    const __bf16* __restrict__ W2T, const float* __restrict__ b2,
    float* __restrict__ phi, int E, int EB, int N)
{
    __shared__ __bf16 t_lds[16 * TLDS_STRIDE];   // mlp only; 4.3 KB

    const int tid = threadIdx.x;
    const int b   = blockIdx.x;

    if (b < EB) {                       // ---- build
        const int e = b * 256 + tid;
        if (e >= E) return;
        const int2 nb = ((const int2*)nbrs)[e];
        const int dst = nb.x;
        const int src = nb.y;
        const int slot = atomicAdd(&cnt[dst], 1);
        if (slot >= CAP) return;

        const float d = d_ij[e];
        const float x = (float)M_PI * d * (1.0f / CUTOFF);
        float sx, cx;
        __sincosf(x, &sx, &cx);
        const float fcut = (d < CUTOFF) ? 0.5f * (cx + 1.0f) : 0.0f;
        float4 q0, q1;
        q0.x = sx * fcut / d;           // rbff_1; recurrence keeps fcut/d scale
        q0.y = 2.0f * cx;
        q0.z = fcut;
        q0.w = unit_r[3 * e + 0];
        q1.x = unit_r[3 * e + 1];
        q1.y = unit_r[3 * e + 2];
        q1.z = __int_as_float(src);
        q1.w = 0.0f;
        float4* pk = (float4*)(pack + ((size_t)dst * CAP + slot) * 8);
        pk[0] = q0;
        pk[1] = q1;
        return;
    }

    // ---- mlp
    const int wave = tid >> 6;
    const int lane = tid & 63;
    const int m    = lane & 15;
    const int quad = lane >> 4;
    const int node0 = (b - EB) * 16;
    if (node0 >= N) return;

    bf16x8 a1[4];
    #pragma unroll
    for (int kb = 0; kb < 4; ++kb) {
        const float* hp = h + (size_t)(node0 + m) * F + kb * 32 + quad * 8;
        const float4 x0 = *(const float4*)hp;
        const float4 x1 = *(const float4*)(hp + 4);
        bf16x8 a;
        a[0] = (__bf16)x0.x; a[1] = (__bf16)x0.y;
        a[2] = (__bf16)x0.z; a[3] = (__bf16)x0.w;
        a[4] = (__bf16)x1.x; a[5] = (__bf16)x1.y;
        a[6] = (__bf16)x1.z; a[7] = (__bf16)x1.w;
        a1[kb] = a;
    }

    // W1 + silu: 8 ct tiles, 2 per wave, into shared t
    #pragma unroll
    for (int c2 = 0; c2 < 2; ++c2) {
        const int ct = wave * 2 + c2;
        f32x4 acc = {0.0f, 0.0f, 0.0f, 0.0f};
        #pragma unroll
        for (int kb = 0; kb < 4; ++kb) {
            const bf16x8 bb =
                *(const bf16x8*)(W1T + (size_t)(ct * 16 + m) * F + kb * 32 + quad * 8);
            acc = __builtin_amdgcn_mfma_f32_16x16x32_bf16(a1[kb], bb, acc, 0, 0, 0);
        }
        const int col = ct * 16 + m;
        const float bb = b1[col];
        #pragma unroll
        for (int reg = 0; reg < 4; ++reg) {
            const float x = acc[reg] + bb;
            const float s = x / (1.0f + __expf(-x));
            t_lds[(quad * 4 + reg) * TLDS_STRIDE + col] = (__bf16)s;
        }
    }
    __syncthreads();

    bf16x8 a2[4];
    #pragma unroll
    for (int kb = 0; kb < 4; ++kb)
        a2[kb] = *(const bf16x8*)&t_lds[m * TLDS_STRIDE + kb * 32 + quad * 8];

    // W2: 24 ct tiles, 6 per wave
    #pragma unroll
    for (int c6 = 0; c6 < 6; ++c6) {
        const int ct = c6 * 4 + wave;
        f32x4 acc = {0.0f, 0.0f, 0.0f, 0.0f};
        #pragma unroll
        for (int kb = 0; kb < 4; ++kb) {
            const bf16x8 bb =
                *(const bf16x8*)(W2T + (size_t)(ct * 16 + m) * F + kb * 32 + quad * 8);
            acc = __builtin_amdgcn_mfma_f32_16x16x32_bf16(a2[kb], bb, acc, 0, 0, 0);
        }
        const int col   = ct * 16 + m;
        const int plane = col >> 7;
        const int fc    = col & 127;
        const float bb  = b2[col];
        float* pp = phi + (size_t)plane * N * F + fc;
        #pragma unroll
        for (int reg = 0; reg < 4; ++reg) {
            const int row = quad * 4 + reg;
            pp[(size_t)(node0 + row) * F] = acc[reg] + bb;
        }
    }
}

// ---------------------------------------------------------------------------
// Gather: 256 threads = 2 nodes/block. Base = verified R0 structure (143-145
// us, VALU 79%). R7 delta: shared-RBF done RIGHT (R2's version lost to
// confounds: reg-pins->AGPR shuffling, scalar ds reads, phi4 fetch bloat):
//  - s_rbf filled once per node (one wave, 20 serial FMA, amortized over
//    ~16 edges); inner loop replaces the 20-FMA recurrence with 5
//    wave-uniform broadcast ds_read_b128 (conflict-free).
//  - per-edge pack reads collapsed from 7 scalar ds reads to 2 ds_read_b128.
//  - planar phi, per-edge VMEM WrT reads, 14.3 KB LDS (occ 37% verified R2).
// ---------------------------------------------------------------------------
__global__ __launch_bounds__(256) void gather_kernel(
    const float* __restrict__ phi,       // 3 planes of (N,128)
    const float* __restrict__ v_i,       // (N,128,3)
    const float* __restrict__ WrT,       // (5,3,128,4) chunked transpose
    const float* __restrict__ br,        // (384)
    const int*   __restrict__ cnt,       // (N)
    const float* __restrict__ pack,      // (N,CAP,8)
    float* __restrict__ dh,              // (N,128)
    float* __restrict__ dv,              // (N,128,3)
    int N)
{
    __shared__ float4 s_pack[2][CAP * 2];   // 4 KB
    __shared__ float  s_rbf[2][CAP * 20];   // 10 KB; row stride 80 B (16B-mult)

    const int tid  = threadIdx.x;
    const int half = tid >> 7;
    const int f    = tid & 127;
    const int node = blockIdx.x * 2 + half;

    const int deg0 = cnt[node];
    const int deg  = deg0 < CAP ? deg0 : CAP;

    {   // stage this node's pack rows: deg*2 float4s, coalesced
        const float4* src = (const float4*)(pack + (size_t)node * CAP * 8);
        if (f < 2 * deg) s_pack[half][f] = src[f];
    }
    __syncthreads();

    // one thread per edge slot expands the sin-recurrence (identical for all
    // 128 f-threads of the node -> compute once, not 128x)
    if (f < deg) {
        const float* q = (const float*)&s_pack[half][2 * f];
        float rp = 0.0f, rc = q[0];
        const float twoc = q[1];
        float* rb = &s_rbf[half][f * 20];
        rb[0] = rc;
        #pragma unroll
        for (int n = 1; n < 20; ++n) {
            const float rn = fmaf(twoc, rc, -rp);
            rp = rc; rc = rn;
            rb[n] = rn;
        }
    }
    __syncthreads();

    const float br0 = br[f], br1 = br[f + 128], br2 = br[f + 256];

    const float* phi0 = phi;
    const float* phi1 = phi + (size_t)N * F;
    const float* phi2 = phi + (size_t)2 * N * F;
    const float4* wT  = (const float4*)WrT;   // wT[(n4*3 + c)*128 + f]

    float dh_acc = 0.0f, dv0 = 0.0f, dv1 = 0.0f, dv2 = 0.0f;

    for (int i = 0; i < deg; ++i) {
        const float4 q0 = s_pack[half][2 * i];
        const float4 q1 = s_pack[half][2 * i + 1];
        const float fcut = q0.z;
        const float ux   = q0.w;
        const float uy   = q1.x;
        const float uz   = q1.y;
        // LDS value -> SGPR: only lgkmcnt wait, global-load queue stays full
        const int src = __builtin_amdgcn_readfirstlane(__float_as_int(q1.z));

        float a0 = br0 * fcut, a1 = br1 * fcut, a2 = br2 * fcut;
        #pragma unroll
        for (int n4 = 0; n4 < 5; ++n4) {
            const float4 w0 = wT[(n4 * 3 + 0) * 128 + f];
            const float4 w1 = wT[(n4 * 3 + 1) * 128 + f];
            const float4 w2 = wT[(n4 * 3 + 2) * 128 + f];
            // wave-uniform address -> broadcast, conflict-free
            const float4 rb = *(const float4*)&s_rbf[half][i * 20 + n4 * 4];
            a0 = fmaf(rb.x, w0.x, a0);
            a1 = fmaf(rb.x, w1.x, a1);
            a2 = fmaf(rb.x, w2.x, a2);
            a0 = fmaf(rb.y, w0.y, a0);
            a1 = fmaf(rb.y, w1.y, a1);
            a2 = fmaf(rb.y, w2.y, a2);
            a0 = fmaf(rb.z, w0.z, a0);
            a1 = fmaf(rb.z, w1.z, a1);
            a2 = fmaf(rb.z, w2.z, a2);
            a0 = fmaf(rb.w, w0.w, a0);
            a1 = fmaf(rb.w, w1.w, a1);
            a2 = fmaf(rb.w, w2.w, a2);
        }

        const float f1 = phi0[(size_t)src * F + f] * a0;
        const float f2 = phi1[(size_t)src * F + f] * a1;
        const float f3 = phi2[(size_t)src * F + f] * a2;

        dh_acc += f3;

        const float* vs = v_i + (size_t)src * THREEF + 3 * f;
        dv0 = fmaf(f1, ux, fmaf(f2, vs[0], dv0));
        dv1 = fmaf(f1, uy, fmaf(f2, vs[1], dv1));
        dv2 = fmaf(f1, uz, fmaf(f2, vs[2], dv2));
    }

    dh[(size_t)node * F + f] = dh_acc;
    float* dvp = dv + (size_t)node * THREEF + 3 * f;
    dvp[0] = dv0;
    dvp[1] = dv1;
    dvp[2] = dv2;
}

extern "C" void kernel_launch(void* const* d_in, const int* in_sizes, int n_in,
                              void* d_out, int out_size, void* d_ws, size_t ws_size,
                              hipStream_t stream) {
    const float* h_i    = (const float*)d_in[0];
    const float* v_i    = (const float*)d_in[1];
    const float* d_ij   = (const float*)d_in[2];
    const float* unit_r = (const float*)d_in[3];
    const int*   nbrs   = (const int*)  d_in[4];
    const float* W1     = (const float*)d_in[5];
    const float* b1     = (const float*)d_in[6];
    const float* W2     = (const float*)d_in[7];
    const float* b2     = (const float*)d_in[8];
    const float* Wr     = (const float*)d_in[9];
    const float* br     = (const float*)d_in[10];

    const int N = in_sizes[0] / F;       // 20000
    const int E = in_sizes[2];           // 320000

    float* dh = (float*)d_out;              // (N,128)
    float* dv = dh + (size_t)N * F;         // (N,128,3)

    // workspace: phi (3NF) | pack (N*CAP*8) | WrT | cnt | W1T | W2T
    float*  phi  = (float*)d_ws;                           // 30.7 MB
    float*  pack = phi + (size_t)3 * N * F;                // 41 MB
    float*  WrT  = pack + (size_t)N * CAP * 8;             // 30 KB
    int*    cnt  = (int*)(WrT + 5 * 3 * 128 * 4);          // 80 KB
    __bf16* W1T  = (__bf16*)(cnt + N);                     // 32 KB
    __bf16* W2T  = W1T + 128 * 128;                        // 96 KB

    const int EB = (E + 255) / 256;      // 1250 build blocks
    const int MB = (N + 15) / 16;        // 1250 mlp blocks
    const int ZB = ((N + 3) / 4 + 255) / 256;   // cnt-zero blocks (20)

    init_kernel<<<256 + 8 + ZB, 256, 0, stream>>>(W1, W2, Wr, W1T, W2T, WrT,
                                                  cnt, N);
    work_kernel<<<EB + MB, 256, 0, stream>>>(d_ij, unit_r, nbrs, cnt, pack,
                                             h_i, W1T, b1, W2T, b2, phi,
                                             E, EB, N);
    gather_kernel<<<N / 2, 256, 0, stream>>>(phi, v_i, WrT, br, cnt, pack,
                                             dh, dv, N);
}

// Round 8
// 286.219 us; speedup vs baseline: 1.0266x; 1.0266x over previous
//
#include <hip/hip_runtime.h>
#include <math.h>

#define F 128
#define THREEF 384
#define N_RBF 20
#define CUTOFF 5.0f
#define CAP 64
#define TLDS_STRIDE 136   // shorts; 272 B row: 16B-aligned, ~2-way banks (free)

typedef __bf16 bf16x8 __attribute__((ext_vector_type(8)));
typedef float  f32x4  __attribute__((ext_vector_type(4)));
typedef float  f32x2  __attribute__((ext_vector_type(2)));

// ---------------------------------------------------------------------------
// Init (replaces the cnt-memset dispatch; no dependency on anything):
//   blocks [0,256)    : wcast — W1,W2 -> bf16 k-major
//   blocks [256,264)  : wrt — chunked transpose of Wr for gather
//   blocks [264,...)  : zero cnt (int4 stores)
// ---------------------------------------------------------------------------
__global__ __launch_bounds__(256) void init_kernel(
    const float* __restrict__ W1, const float* __restrict__ W2,
    const float* __restrict__ Wr,
    __bf16* __restrict__ W1T, __bf16* __restrict__ W2T,
    float* __restrict__ WrT, int* __restrict__ cnt, int N)
{
    const int tid = threadIdx.x;
    const int b   = blockIdx.x;

    if (b < 256) {                      // ---- wcast
        const int idx = b * 256 + tid;
        if (idx < 128 * 128) {
            const int n = idx >> 7, k = idx & 127;
            W1T[idx] = (__bf16)W1[k * F + n];
        }
        if (idx < 384 * 128) {
            const int n = idx >> 7, k = idx & 127;
            W2T[idx] = (__bf16)W2[k * THREEF + n];
        }
    } else if (b < 264) {               // ---- wrt
        const int idx = (b - 256) * 256 + tid;   // 0..2047
        if (idx >= 5 * 3 * 128) return;
        const int f  = idx & 127;
        const int c  = (idx >> 7) % 3;
        const int n4 = idx / (3 * 128);
        float4 v;
        v.x = Wr[(4 * n4 + 0) * THREEF + c * 128 + f];
        v.y = Wr[(4 * n4 + 1) * THREEF + c * 128 + f];
        v.z = Wr[(4 * n4 + 2) * THREEF + c * 128 + f];
        v.w = Wr[(4 * n4 + 3) * THREEF + c * 128 + f];
        ((float4*)WrT)[idx] = v;
    } else {                            // ---- zero cnt
        const int i = (b - 264) * 256 + tid;
        if (i < (N + 3) / 4) {
            int4 z; z.x = 0; z.y = 0; z.z = 0; z.w = 0;
            ((int4*)cnt)[i] = z;
        }
    }
}

// ---------------------------------------------------------------------------
// Work (build ∥ mlp as CONCURRENT block ranges — data-independent; both
// depend only on init_kernel's outputs):
//   blocks [0, EB)       : build — CSR slot via atomic, pack row written at
//                          (dst,slot): {s1, 2cos(x), fcut, ux, uy, uz, src, 0}
//   blocks [EB, EB+MB)   : mlp — phi = silu(h@W1+b1)@W2 + b2 via bf16 MFMA,
//                          3 planes [c][node][f]; 4 waves cooperate on the
//                          same 16 nodes (R6 occupancy fix, verified)
// ---------------------------------------------------------------------------
__global__ __launch_bounds__(256) void work_kernel(
    const float* __restrict__ d_ij, const float* __restrict__ unit_r,
    const int* __restrict__ nbrs,
    int* __restrict__ cnt, float* __restrict__ pack,
    const float* __restrict__ h,
    const __bf16* __restrict__ W1T, const float* __restrict__ b1,
    const __bf16* __restrict__ W2T, const float* __restrict__ b2,
    float* __restrict__ phi, int E, int EB, int N)
{
    __shared__ __bf16 t_lds[16 * TLDS_STRIDE];   // mlp only; 4.3 KB

    const int tid = threadIdx.x;
    const int b   = blockIdx.x;

    if (b < EB) {                       // ---- build
        const int e = b * 256 + tid;
        if (e >= E) return;
        const int2 nb = ((const int2*)nbrs)[e];
        const int dst = nb.x;
        const int src = nb.y;
        const int slot = atomicAdd(&cnt[dst], 1);
        if (slot >= CAP) return;

        const float d = d_ij[e];
        const float x = (float)M_PI * d * (1.0f / CUTOFF);
        float sx, cx;
        __sincosf(x, &sx, &cx);
        const float fcut = (d < CUTOFF) ? 0.5f * (cx + 1.0f) : 0.0f;
        float4 q0, q1;
        q0.x = sx * fcut / d;           // rbff_1; recurrence keeps fcut/d scale
        q0.y = 2.0f * cx;
        q0.z = fcut;
        q0.w = unit_r[3 * e + 0];
        q1.x = unit_r[3 * e + 1];
        q1.y = unit_r[3 * e + 2];
        q1.z = __int_as_float(src);
        q1.w = 0.0f;
        float4* pk = (float4*)(pack + ((size_t)dst * CAP + slot) * 8);
        pk[0] = q0;
        pk[1] = q1;
        return;
    }

    // ---- mlp
    const int wave = tid >> 6;
    const int lane = tid & 63;
    const int m    = lane & 15;
    const int quad = lane >> 4;
    const int node0 = (b - EB) * 16;
    if (node0 >= N) return;

    bf16x8 a1[4];
    #pragma unroll
    for (int kb = 0; kb < 4; ++kb) {
        const float* hp = h + (size_t)(node0 + m) * F + kb * 32 + quad * 8;
        const float4 x0 = *(const float4*)hp;
        const float4 x1 = *(const float4*)(hp + 4);
        bf16x8 a;
        a[0] = (__bf16)x0.x; a[1] = (__bf16)x0.y;
        a[2] = (__bf16)x0.z; a[3] = (__bf16)x0.w;
        a[4] = (__bf16)x1.x; a[5] = (__bf16)x1.y;
        a[6] = (__bf16)x1.z; a[7] = (__bf16)x1.w;
        a1[kb] = a;
    }

    // W1 + silu: 8 ct tiles, 2 per wave, into shared t
    #pragma unroll
    for (int c2 = 0; c2 < 2; ++c2) {
        const int ct = wave * 2 + c2;
        f32x4 acc = {0.0f, 0.0f, 0.0f, 0.0f};
        #pragma unroll
        for (int kb = 0; kb < 4; ++kb) {
            const bf16x8 bb =
                *(const bf16x8*)(W1T + (size_t)(ct * 16 + m) * F + kb * 32 + quad * 8);
            acc = __builtin_amdgcn_mfma_f32_16x16x32_bf16(a1[kb], bb, acc, 0, 0, 0);
        }
        const int col = ct * 16 + m;
        const float bb = b1[col];
        #pragma unroll
        for (int reg = 0; reg < 4; ++reg) {
            const float x = acc[reg] + bb;
            const float s = x / (1.0f + __expf(-x));
            t_lds[(quad * 4 + reg) * TLDS_STRIDE + col] = (__bf16)s;
        }
    }
    __syncthreads();

    bf16x8 a2[4];
    #pragma unroll
    for (int kb = 0; kb < 4; ++kb)
        a2[kb] = *(const bf16x8*)&t_lds[m * TLDS_STRIDE + kb * 32 + quad * 8];

    // W2: 24 ct tiles, 6 per wave
    #pragma unroll
    for (int c6 = 0; c6 < 6; ++c6) {
        const int ct = c6 * 4 + wave;
        f32x4 acc = {0.0f, 0.0f, 0.0f, 0.0f};
        #pragma unroll
        for (int kb = 0; kb < 4; ++kb) {
            const bf16x8 bb =
                *(const bf16x8*)(W2T + (size_t)(ct * 16 + m) * F + kb * 32 + quad * 8);
            acc = __builtin_amdgcn_mfma_f32_16x16x32_bf16(a2[kb], bb, acc, 0, 0, 0);
        }
        const int col   = ct * 16 + m;
        const int plane = col >> 7;
        const int fc    = col & 127;
        const float bb  = b2[col];
        float* pp = phi + (size_t)plane * N * F + fc;
        #pragma unroll
        for (int reg = 0; reg < 4; ++reg) {
            const int row = quad * 4 + reg;
            pp[(size_t)(node0 + row) * F] = acc[reg] + bb;
        }
    }
}

// ---------------------------------------------------------------------------
// Gather: 256 threads = 2 nodes/block. Base = EXACT R0 structure (verified
// 143-147 us, VALU 79%, VGPR 52, 4 KB LDS). R8 delta: the 80-FMA chain per
// edge (60 contraction + 20 recurrence) is rewritten as 40 PACKED f32x2 ops
// (v_pk_fma_f32, gfx90a+). The serial sin-recurrence is split into two
// independent chains via the Chebyshev double-step
//     r_{n+2} = (twoc^2 - 2) * r_n - r_{n-2}
// with seeds (r1, r2=twoc*r1) / (r_{-1}=-r1, r0=0), so the pair
// (r_{2j+1}, r_{2j+2}) lines up with the existing WrT float4 component
// pairs (x,y)/(z,w) — no layout change, no cross-lane shuffles.
// All previous LDS/blocking restructurings lost (R2/R3/R4/R5/R7); this one
// keeps structure identical and only thins VALU issue count (~133 -> ~95).
// ---------------------------------------------------------------------------
__global__ __launch_bounds__(256) void gather_kernel(
    const float* __restrict__ phi,       // 3 planes of (N,128)
    const float* __restrict__ v_i,       // (N,128,3)
    const float* __restrict__ WrT,       // (5,3,128,4) chunked transpose
    const float* __restrict__ br,        // (384)
    const int*   __restrict__ cnt,       // (N)
    const float* __restrict__ pack,      // (N,CAP,8)
    float* __restrict__ dh,              // (N,128)
    float* __restrict__ dv,              // (N,128,3)
    int N)
{
    __shared__ float4 s_pack[2][CAP * 2];   // 4 KB

    const int tid  = threadIdx.x;
    const int half = tid >> 7;
    const int f    = tid & 127;
    const int node = blockIdx.x * 2 + half;

    const int deg0 = cnt[node];
    const int deg  = deg0 < CAP ? deg0 : CAP;

    {   // stage this node's pack rows: deg*2 float4s, coalesced
        const float4* src = (const float4*)(pack + (size_t)node * CAP * 8);
        if (f < 2 * deg) s_pack[half][f] = src[f];
    }
    __syncthreads();

    const float br0 = br[f], br1 = br[f + 128], br2 = br[f + 256];

    const float* phi0 = phi;
    const float* phi1 = phi + (size_t)N * F;
    const float* phi2 = phi + (size_t)2 * N * F;
    const f32x4* wT   = (const f32x4*)WrT;   // wT[(n4*3 + c)*128 + f]

    float dh_acc = 0.0f, dv0 = 0.0f, dv1 = 0.0f, dv2 = 0.0f;

    for (int i = 0; i < deg; ++i) {
        const float* q = (const float*)&s_pack[half][2 * i];
        const float s1   = q[0];
        const float twoc = q[1];
        const float fcut = q[2];
        const float ux   = q[3];
        const float uy   = q[4];
        const float uz   = q[5];
        // LDS value -> SGPR: only lgkmcnt wait, global-load queue stays full
        const int src = __builtin_amdgcn_readfirstlane(__float_as_int(q[6]));

        // double-step Chebyshev: two independent chains, packed in f32x2
        const float t2s = fmaf(twoc, twoc, -2.0f);
        f32x2 t2; t2[0] = t2s;  t2[1] = t2s;
        f32x2 rc; rc[0] = s1;   rc[1] = twoc * s1;   // (r1, r2)
        f32x2 rp; rp[0] = -s1;  rp[1] = 0.0f;        // (r_-1, r0)
        f32x2 A0 = {0.0f, 0.0f}, A1 = {0.0f, 0.0f}, A2 = {0.0f, 0.0f};

        #pragma unroll
        for (int n4 = 0; n4 < 5; ++n4) {
            const f32x4 w0 = wT[(n4 * 3 + 0) * 128 + f];
            const f32x4 w1 = wT[(n4 * 3 + 1) * 128 + f];
            const f32x4 w2 = wT[(n4 * 3 + 2) * 128 + f];
            // step 1: rc = (r_{4n4+1}, r_{4n4+2}) x (w.x, w.y)
            A0 = __builtin_elementwise_fma(rc, __builtin_shufflevector(w0, w0, 0, 1), A0);
            A1 = __builtin_elementwise_fma(rc, __builtin_shufflevector(w1, w1, 0, 1), A1);
            A2 = __builtin_elementwise_fma(rc, __builtin_shufflevector(w2, w2, 0, 1), A2);
            f32x2 rn = __builtin_elementwise_fma(t2, rc, -rp);
            rp = rc; rc = rn;
            // step 2: rc = (r_{4n4+3}, r_{4n4+4}) x (w.z, w.w)
            A0 = __builtin_elementwise_fma(rc, __builtin_shufflevector(w0, w0, 2, 3), A0);
            A1 = __builtin_elementwise_fma(rc, __builtin_shufflevector(w1, w1, 2, 3), A1);
            A2 = __builtin_elementwise_fma(rc, __builtin_shufflevector(w2, w2, 2, 3), A2);
            rn = __builtin_elementwise_fma(t2, rc, -rp);
            rp = rc; rc = rn;
        }

        const float a0 = fmaf(br0, fcut, A0[0] + A0[1]);
        const float a1 = fmaf(br1, fcut, A1[0] + A1[1]);
        const float a2 = fmaf(br2, fcut, A2[0] + A2[1]);

        const float f1 = phi0[(size_t)src * F + f] * a0;
        const float f2 = phi1[(size_t)src * F + f] * a1;
        const float f3 = phi2[(size_t)src * F + f] * a2;

        dh_acc += f3;

        const float* vs = v_i + (size_t)src * THREEF + 3 * f;
        dv0 = fmaf(f1, ux, fmaf(f2, vs[0], dv0));
        dv1 = fmaf(f1, uy, fmaf(f2, vs[1], dv1));
        dv2 = fmaf(f1, uz, fmaf(f2, vs[2], dv2));
    }

    dh[(size_t)node * F + f] = dh_acc;
    float* dvp = dv + (size_t)node * THREEF + 3 * f;
    dvp[0] = dv0;
    dvp[1] = dv1;
    dvp[2] = dv2;
}

extern "C" void kernel_launch(void* const* d_in, const int* in_sizes, int n_in,
                              void* d_out, int out_size, void* d_ws, size_t ws_size,
                              hipStream_t stream) {
    const float* h_i    = (const float*)d_in[0];
    const float* v_i    = (const float*)d_in[1];
    const float* d_ij   = (const float*)d_in[2];
    const float* unit_r = (const float*)d_in[3];
    const int*   nbrs   = (const int*)  d_in[4];
    const float* W1     = (const float*)d_in[5];
    const float* b1     = (const float*)d_in[6];
    const float* W2     = (const float*)d_in[7];
    const float* b2     = (const float*)d_in[8];
    const float* Wr     = (const float*)d_in[9];
    const float* br     = (const float*)d_in[10];

    const int N = in_sizes[0] / F;       // 20000
    const int E = in_sizes[2];           // 320000

    float* dh = (float*)d_out;              // (N,128)
    float* dv = dh + (size_t)N * F;         // (N,128,3)

    // workspace: phi (3NF) | pack (N*CAP*8) | WrT | cnt | W1T | W2T
    float*  phi  = (float*)d_ws;                           // 30.7 MB
    float*  pack = phi + (size_t)3 * N * F;                // 41 MB
    float*  WrT  = pack + (size_t)N * CAP * 8;             // 30 KB
    int*    cnt  = (int*)(WrT + 5 * 3 * 128 * 4);          // 80 KB
    __bf16* W1T  = (__bf16*)(cnt + N);                     // 32 KB
    __bf16* W2T  = W1T + 128 * 128;                        // 96 KB

    const int EB = (E + 255) / 256;      // 1250 build blocks
    const int MB = (N + 15) / 16;        // 1250 mlp blocks
    const int ZB = ((N + 3) / 4 + 255) / 256;   // cnt-zero blocks (20)

    init_kernel<<<256 + 8 + ZB, 256, 0, stream>>>(W1, W2, Wr, W1T, W2T, WrT,
                                                  cnt, N);
    work_kernel<<<EB + MB, 256, 0, stream>>>(d_ij, unit_r, nbrs, cnt, pack,
                                             h_i, W1T, b1, W2T, b2, phi,
                                             E, EB, N);
    gather_kernel<<<N / 2, 256, 0, stream>>>(phi, v_i, WrT, br, cnt, pack,
                                             dh, dv, N);
}

// Round 9
// 281.002 us; speedup vs baseline: 1.0457x; 1.0186x over previous
//
#include <hip/hip_runtime.h>
#include <math.h>

#define F 128
#define THREEF 384
#define N_RBF 20
#define CUTOFF 5.0f
#define CAP 64
#define TLDS_STRIDE 136   // shorts; 272 B row: 16B-aligned, ~2-way banks (free)

typedef __bf16 bf16x8 __attribute__((ext_vector_type(8)));
typedef float  f32x4  __attribute__((ext_vector_type(4)));
typedef float  f32x2  __attribute__((ext_vector_type(2)));

// ---------------------------------------------------------------------------
// Init (replaces the cnt-memset dispatch; no dependency on anything):
//   blocks [0,256)    : wcast — W1,W2 -> bf16 k-major
//   blocks [256,264)  : wrt — chunked transpose of Wr for gather
//   blocks [264,...)  : zero cnt (int4 stores)
// ---------------------------------------------------------------------------
__global__ __launch_bounds__(256) void init_kernel(
    const float* __restrict__ W1, const float* __restrict__ W2,
    const float* __restrict__ Wr,
    __bf16* __restrict__ W1T, __bf16* __restrict__ W2T,
    float* __restrict__ WrT, int* __restrict__ cnt, int N)
{
    const int tid = threadIdx.x;
    const int b   = blockIdx.x;

    if (b < 256) {                      // ---- wcast
        const int idx = b * 256 + tid;
        if (idx < 128 * 128) {
            const int n = idx >> 7, k = idx & 127;
            W1T[idx] = (__bf16)W1[k * F + n];
        }
        if (idx < 384 * 128) {
            const int n = idx >> 7, k = idx & 127;
            W2T[idx] = (__bf16)W2[k * THREEF + n];
        }
    } else if (b < 264) {               // ---- wrt
        const int idx = (b - 256) * 256 + tid;   // 0..2047
        if (idx >= 5 * 3 * 128) return;
        const int f  = idx & 127;
        const int c  = (idx >> 7) % 3;
        const int n4 = idx / (3 * 128);
        float4 v;
        v.x = Wr[(4 * n4 + 0) * THREEF + c * 128 + f];
        v.y = Wr[(4 * n4 + 1) * THREEF + c * 128 + f];
        v.z = Wr[(4 * n4 + 2) * THREEF + c * 128 + f];
        v.w = Wr[(4 * n4 + 3) * THREEF + c * 128 + f];
        ((float4*)WrT)[idx] = v;
    } else {                            // ---- zero cnt
        const int i = (b - 264) * 256 + tid;
        if (i < (N + 3) / 4) {
            int4 z; z.x = 0; z.y = 0; z.z = 0; z.w = 0;
            ((int4*)cnt)[i] = z;
        }
    }
}

// ---------------------------------------------------------------------------
// Work (build ∥ mlp as CONCURRENT block ranges — data-independent; both
// depend only on init_kernel's outputs):
//   blocks [0, EB)       : build — CSR slot via atomic, pack row written at
//                          (dst,slot): {s1, 2cos(x), fcut, ux, uy, uz, src, 0}
//   blocks [EB, EB+MB)   : mlp — phi = silu(h@W1+b1)@W2 + b2 via bf16 MFMA.
// R9: phi stored NODE-MAJOR (N,3,128) so the gather reads all 3 planes from
// ONE scalar-computed address with offset:512/1024 immediates.
// ---------------------------------------------------------------------------
__global__ __launch_bounds__(256) void work_kernel(
    const float* __restrict__ d_ij, const float* __restrict__ unit_r,
    const int* __restrict__ nbrs,
    int* __restrict__ cnt, float* __restrict__ pack,
    const float* __restrict__ h,
    const __bf16* __restrict__ W1T, const float* __restrict__ b1,
    const __bf16* __restrict__ W2T, const float* __restrict__ b2,
    float* __restrict__ phi, int E, int EB, int N)
{
    __shared__ __bf16 t_lds[16 * TLDS_STRIDE];   // mlp only; 4.3 KB

    const int tid = threadIdx.x;
    const int b   = blockIdx.x;

    if (b < EB) {                       // ---- build
        const int e = b * 256 + tid;
        if (e >= E) return;
        const int2 nb = ((const int2*)nbrs)[e];
        const int dst = nb.x;
        const int src = nb.y;
        const int slot = atomicAdd(&cnt[dst], 1);
        if (slot >= CAP) return;

        const float d = d_ij[e];
        const float x = (float)M_PI * d * (1.0f / CUTOFF);
        float sx, cx;
        __sincosf(x, &sx, &cx);
        const float fcut = (d < CUTOFF) ? 0.5f * (cx + 1.0f) : 0.0f;
        float4 q0, q1;
        q0.x = sx * fcut / d;           // rbff_1; recurrence keeps fcut/d scale
        q0.y = 2.0f * cx;
        q0.z = fcut;
        q0.w = unit_r[3 * e + 0];
        q1.x = unit_r[3 * e + 1];
        q1.y = unit_r[3 * e + 2];
        q1.z = __int_as_float(src);
        q1.w = 0.0f;
        float4* pk = (float4*)(pack + ((size_t)dst * CAP + slot) * 8);
        pk[0] = q0;
        pk[1] = q1;
        return;
    }

    // ---- mlp
    const int wave = tid >> 6;
    const int lane = tid & 63;
    const int m    = lane & 15;
    const int quad = lane >> 4;
    const int node0 = (b - EB) * 16;
    if (node0 >= N) return;

    bf16x8 a1[4];
    #pragma unroll
    for (int kb = 0; kb < 4; ++kb) {
        const float* hp = h + (size_t)(node0 + m) * F + kb * 32 + quad * 8;
        const float4 x0 = *(const float4*)hp;
        const float4 x1 = *(const float4*)(hp + 4);
        bf16x8 a;
        a[0] = (__bf16)x0.x; a[1] = (__bf16)x0.y;
        a[2] = (__bf16)x0.z; a[3] = (__bf16)x0.w;
        a[4] = (__bf16)x1.x; a[5] = (__bf16)x1.y;
        a[6] = (__bf16)x1.z; a[7] = (__bf16)x1.w;
        a1[kb] = a;
    }

    // W1 + silu: 8 ct tiles, 2 per wave, into shared t
    #pragma unroll
    for (int c2 = 0; c2 < 2; ++c2) {
        const int ct = wave * 2 + c2;
        f32x4 acc = {0.0f, 0.0f, 0.0f, 0.0f};
        #pragma unroll
        for (int kb = 0; kb < 4; ++kb) {
            const bf16x8 bb =
                *(const bf16x8*)(W1T + (size_t)(ct * 16 + m) * F + kb * 32 + quad * 8);
            acc = __builtin_amdgcn_mfma_f32_16x16x32_bf16(a1[kb], bb, acc, 0, 0, 0);
        }
        const int col = ct * 16 + m;
        const float bb = b1[col];
        #pragma unroll
        for (int reg = 0; reg < 4; ++reg) {
            const float x = acc[reg] + bb;
            const float s = x / (1.0f + __expf(-x));
            t_lds[(quad * 4 + reg) * TLDS_STRIDE + col] = (__bf16)s;
        }
    }
    __syncthreads();

    bf16x8 a2[4];
    #pragma unroll
    for (int kb = 0; kb < 4; ++kb)
        a2[kb] = *(const bf16x8*)&t_lds[m * TLDS_STRIDE + kb * 32 + quad * 8];

    // W2: 24 ct tiles, 6 per wave; phi write node-major (N,3,128)
    #pragma unroll
    for (int c6 = 0; c6 < 6; ++c6) {
        const int ct = c6 * 4 + wave;
        f32x4 acc = {0.0f, 0.0f, 0.0f, 0.0f};
        #pragma unroll
        for (int kb = 0; kb < 4; ++kb) {
            const bf16x8 bb =
                *(const bf16x8*)(W2T + (size_t)(ct * 16 + m) * F + kb * 32 + quad * 8);
            acc = __builtin_amdgcn_mfma_f32_16x16x32_bf16(a2[kb], bb, acc, 0, 0, 0);
        }
        const int col = ct * 16 + m;          // = plane*128 + fc
        const float bb = b2[col];
        #pragma unroll
        for (int reg = 0; reg < 4; ++reg) {
            const int row = quad * 4 + reg;
            phi[(size_t)(node0 + row) * THREEF + col] = acc[reg] + bb;
        }
    }
}

// ---------------------------------------------------------------------------
// Gather: 256 threads = 2 nodes/block.
// R8 post-mortem: VALU cut 30% -> dur unchanged => L1-BW-bound on WrT
// (15 KB/wave-edge of the 16.9 KB total). Fix = amortize WrT in REGISTERS
// across 4 edges. R4 tried this and spilled because the allocator targets
// 8 waves/SIMD (=64 VGPR cap) whenever LDS doesn't cap occupancy — R3's 88
// VGPRs (LDS-capped) proves it CAN exceed 64. amdgpu_waves_per_eu(2,4)
// caps max occupancy at 4 waves/SIMD (50% >= the 45% achieved), removing
// the allocator's incentive to stay at 64.
//  - 4-edge blocking: 15 dwordx4 of WrT per 4 edges (traffic /4).
//  - packed f32x2 Chebyshev double-step (verified R8).
//  - phi node-major (N,3,128) + src in SGPR: per-edge addresses are
//    SALU-computed, planes via offset:512/1024 immediates.
//  - Tail zero-padded: s1=twoc=fcut=u=0 => contribution exactly 0, src=0
//    safe discarded gather address (verified R4/R5 correctness).
// ---------------------------------------------------------------------------
__global__ __launch_bounds__(256)
__attribute__((amdgpu_waves_per_eu(2, 4)))
void gather_kernel(
    const float* __restrict__ phi,       // (N,3,128) node-major
    const float* __restrict__ v_i,       // (N,128,3)
    const float* __restrict__ WrT,       // (5,3,128,4) chunked transpose
    const float* __restrict__ br,        // (384)
    const int*   __restrict__ cnt,       // (N)
    const float* __restrict__ pack,      // (N,CAP,8)
    float* __restrict__ dh,              // (N,128)
    float* __restrict__ dv,              // (N,128,3)
    int N)
{
    __shared__ float4 s_pack[2][CAP * 2];   // 4 KB

    const int tid  = threadIdx.x;
    const int half = tid >> 7;
    const int f    = tid & 127;
    const int node = blockIdx.x * 2 + half;

    const int deg0 = cnt[node];
    const int deg  = deg0 < CAP ? deg0 : CAP;
    const int degR = (deg + 3) & ~3;         // pad to 4-edge blocks (<= CAP)

    {   // stage this node's pack rows; zero the pad slots
        const float4* srcp = (const float4*)(pack + (size_t)node * CAP * 8);
        if (f < 2 * degR) {
            float4 v = make_float4(0.0f, 0.0f, 0.0f, 0.0f);
            if (f < 2 * deg) v = srcp[f];
            s_pack[half][f] = v;
        }
    }
    __syncthreads();

    const float br0 = br[f], br1 = br[f + 128], br2 = br[f + 256];
    const f32x4* wT = (const f32x4*)WrT;   // wT[(n4*3 + c)*128 + f]

    float dh_acc = 0.0f, dvx = 0.0f, dvy = 0.0f, dvz = 0.0f;

    for (int i0 = 0; i0 < degR; i0 += 4) {
        // ---- prologue: per-edge seeds + issue all gather loads (SALU addr)
        float s1[4], twoc[4], fcut[4], ux[4], uy[4], uz[4];
        float ph0[4], ph1[4], ph2[4], vx[4], vy[4], vz[4];
        #pragma unroll
        for (int j = 0; j < 4; ++j) {
            const float4 q0 = s_pack[half][2 * (i0 + j)];
            const float4 q1 = s_pack[half][2 * (i0 + j) + 1];
            s1[j] = q0.x; twoc[j] = q0.y; fcut[j] = q0.z;
            ux[j] = q0.w; uy[j] = q1.x;   uz[j] = q1.y;
            const int src = __builtin_amdgcn_readfirstlane(__float_as_int(q1.z));
            const float* pp = phi + (size_t)src * THREEF + f;
            ph0[j] = pp[0];  ph1[j] = pp[128]; ph2[j] = pp[256];
            const float* vs = v_i + (size_t)src * THREEF + 3 * f;
            vx[j] = vs[0];   vy[j] = vs[1];    vz[j] = vs[2];
        }

        // ---- contraction state: packed Chebyshev double-step (R8-verified)
        f32x2 t2[4], rc[4], rp[4], A0[4], A1[4], A2[4];
        #pragma unroll
        for (int j = 0; j < 4; ++j) {
            const float t2s = fmaf(twoc[j], twoc[j], -2.0f);
            t2[j][0] = t2s;      t2[j][1] = t2s;
            rc[j][0] = s1[j];    rc[j][1] = twoc[j] * s1[j];   // (r1, r2)
            rp[j][0] = -s1[j];   rp[j][1] = 0.0f;              // (r-1, r0)
            A0[j] = (f32x2){0.0f, 0.0f};
            A1[j] = (f32x2){0.0f, 0.0f};
            A2[j] = (f32x2){0.0f, 0.0f};
        }

        #pragma unroll
        for (int n4 = 0; n4 < 5; ++n4) {
            const f32x4 w0 = wT[(n4 * 3 + 0) * 128 + f];
            const f32x4 w1 = wT[(n4 * 3 + 1) * 128 + f];
            const f32x4 w2 = wT[(n4 * 3 + 2) * 128 + f];
            const f32x2 w0lo = __builtin_shufflevector(w0, w0, 0, 1);
            const f32x2 w1lo = __builtin_shufflevector(w1, w1, 0, 1);
            const f32x2 w2lo = __builtin_shufflevector(w2, w2, 0, 1);
            const f32x2 w0hi = __builtin_shufflevector(w0, w0, 2, 3);
            const f32x2 w1hi = __builtin_shufflevector(w1, w1, 2, 3);
            const f32x2 w2hi = __builtin_shufflevector(w2, w2, 2, 3);
            #pragma unroll
            for (int j = 0; j < 4; ++j) {
                A0[j] = __builtin_elementwise_fma(rc[j], w0lo, A0[j]);
                A1[j] = __builtin_elementwise_fma(rc[j], w1lo, A1[j]);
                A2[j] = __builtin_elementwise_fma(rc[j], w2lo, A2[j]);
                f32x2 rn = __builtin_elementwise_fma(t2[j], rc[j], -rp[j]);
                rp[j] = rc[j]; rc[j] = rn;
                A0[j] = __builtin_elementwise_fma(rc[j], w0hi, A0[j]);
                A1[j] = __builtin_elementwise_fma(rc[j], w1hi, A1[j]);
                A2[j] = __builtin_elementwise_fma(rc[j], w2hi, A2[j]);
                rn = __builtin_elementwise_fma(t2[j], rc[j], -rp[j]);
                rp[j] = rc[j]; rc[j] = rn;
            }
        }

        // ---- epilogue
        #pragma unroll
        for (int j = 0; j < 4; ++j) {
            const float a0 = fmaf(br0, fcut[j], A0[j][0] + A0[j][1]);
            const float a1 = fmaf(br1, fcut[j], A1[j][0] + A1[j][1]);
            const float a2 = fmaf(br2, fcut[j], A2[j][0] + A2[j][1]);
            const float f1 = ph0[j] * a0;
            const float f2 = ph1[j] * a1;
            const float f3 = ph2[j] * a2;
            dh_acc += f3;
            dvx = fmaf(f1, ux[j], fmaf(f2, vx[j], dvx));
            dvy = fmaf(f1, uy[j], fmaf(f2, vy[j], dvy));
            dvz = fmaf(f1, uz[j], fmaf(f2, vz[j], dvz));
        }
    }

    dh[(size_t)node * F + f] = dh_acc;
    float* dvp = dv + (size_t)node * THREEF + 3 * f;
    dvp[0] = dvx;
    dvp[1] = dvy;
    dvp[2] = dvz;
}

extern "C" void kernel_launch(void* const* d_in, const int* in_sizes, int n_in,
                              void* d_out, int out_size, void* d_ws, size_t ws_size,
                              hipStream_t stream) {
    const float* h_i    = (const float*)d_in[0];
    const float* v_i    = (const float*)d_in[1];
    const float* d_ij   = (const float*)d_in[2];
    const float* unit_r = (const float*)d_in[3];
    const int*   nbrs   = (const int*)  d_in[4];
    const float* W1     = (const float*)d_in[5];
    const float* b1     = (const float*)d_in[6];
    const float* W2     = (const float*)d_in[7];
    const float* b2     = (const float*)d_in[8];
    const float* Wr     = (const float*)d_in[9];
    const float* br     = (const float*)d_in[10];

    const int N = in_sizes[0] / F;       // 20000
    const int E = in_sizes[2];           // 320000

    float* dh = (float*)d_out;              // (N,128)
    float* dv = dh + (size_t)N * F;         // (N,128,3)

    // workspace: phi (N,3,128) | pack (N*CAP*8) | WrT | cnt | W1T | W2T
    float*  phi  = (float*)d_ws;                           // 30.7 MB
    float*  pack = phi + (size_t)3 * N * F;                // 41 MB
    float*  WrT  = pack + (size_t)N * CAP * 8;             // 30 KB
    int*    cnt  = (int*)(WrT + 5 * 3 * 128 * 4);          // 80 KB
    __bf16* W1T  = (__bf16*)(cnt + N);                     // 32 KB
    __bf16* W2T  = W1T + 128 * 128;                        // 96 KB

    const int EB = (E + 255) / 256;      // 1250 build blocks
    const int MB = (N + 15) / 16;        // 1250 mlp blocks
    const int ZB = ((N + 3) / 4 + 255) / 256;   // cnt-zero blocks (20)

    init_kernel<<<256 + 8 + ZB, 256, 0, stream>>>(W1, W2, Wr, W1T, W2T, WrT,
                                                  cnt, N);
    work_kernel<<<EB + MB, 256, 0, stream>>>(d_ij, unit_r, nbrs, cnt, pack,
                                             h_i, W1T, b1, W2T, b2, phi,
                                             E, EB, N);
    gather_kernel<<<N / 2, 256, 0, stream>>>(phi, v_i, WrT, br, cnt, pack,
                                             dh, dv, N);
}

// Round 10
// 269.479 us; speedup vs baseline: 1.0904x; 1.0428x over previous
//
#include <hip/hip_runtime.h>
#include <math.h>

#define F 128
#define THREEF 384
#define N_RBF 20
#define CUTOFF 5.0f
#define CAP 64
#define TLDS_STRIDE 136   // shorts; 272 B row: 16B-aligned, ~2-way banks (free)

typedef __bf16 bf16x8 __attribute__((ext_vector_type(8)));
typedef float  f32x4  __attribute__((ext_vector_type(4)));
typedef float  f32x2  __attribute__((ext_vector_type(2)));
typedef _Float16 f16x2 __attribute__((ext_vector_type(2)));

static __device__ __forceinline__ float loh(unsigned int u) {
    const f16x2 h = __builtin_bit_cast(f16x2, u);
    return (float)h[0];
}
static __device__ __forceinline__ float hih(unsigned int u) {
    const f16x2 h = __builtin_bit_cast(f16x2, u);
    return (float)h[1];
}

// ---------------------------------------------------------------------------
// Init (replaces the cnt-memset dispatch; no dependency on anything):
//   blocks [0,256)    : wcast — W1,W2 -> bf16 k-major
//   blocks [256,264)  : wrt — chunked transpose of Wr for gather
//   blocks [264,...)  : zero cnt (int4 stores)
// ---------------------------------------------------------------------------
__global__ __launch_bounds__(256) void init_kernel(
    const float* __restrict__ W1, const float* __restrict__ W2,
    const float* __restrict__ Wr,
    __bf16* __restrict__ W1T, __bf16* __restrict__ W2T,
    float* __restrict__ WrT, int* __restrict__ cnt, int N)
{
    const int tid = threadIdx.x;
    const int b   = blockIdx.x;

    if (b < 256) {                      // ---- wcast
        const int idx = b * 256 + tid;
        if (idx < 128 * 128) {
            const int n = idx >> 7, k = idx & 127;
            W1T[idx] = (__bf16)W1[k * F + n];
        }
        if (idx < 384 * 128) {
            const int n = idx >> 7, k = idx & 127;
            W2T[idx] = (__bf16)W2[k * THREEF + n];
        }
    } else if (b < 264) {               // ---- wrt
        const int idx = (b - 256) * 256 + tid;   // 0..2047
        if (idx >= 5 * 3 * 128) return;
        const int f  = idx & 127;
        const int c  = (idx >> 7) % 3;
        const int n4 = idx / (3 * 128);
        float4 v;
        v.x = Wr[(4 * n4 + 0) * THREEF + c * 128 + f];
        v.y = Wr[(4 * n4 + 1) * THREEF + c * 128 + f];
        v.z = Wr[(4 * n4 + 2) * THREEF + c * 128 + f];
        v.w = Wr[(4 * n4 + 3) * THREEF + c * 128 + f];
        ((float4*)WrT)[idx] = v;
    } else {                            // ---- zero cnt
        const int i = (b - 264) * 256 + tid;
        if (i < (N + 3) / 4) {
            int4 z; z.x = 0; z.y = 0; z.z = 0; z.w = 0;
            ((int4*)cnt)[i] = z;
        }
    }
}

// ---------------------------------------------------------------------------
// Work (build ∥ mlp ∥ vcast as CONCURRENT block ranges — data-independent;
// all depend only on init_kernel's outputs):
//   blocks [0, EB)           : build — CSR slot via atomic, pack row at
//                              (dst,slot): {s1,2cos,fcut,ux,uy,uz,src,0}
//   blocks [EB, EB+MB)       : mlp — phi = silu(h@W1+b1)@W2+b2 via bf16
//                              MFMA, written FP16 into the combined record
//   blocks [EB+MB, EB+MB+VB) : vcast — v_i fp32 -> fp16 into the record
// R10: combined gather record gh = (N,128,6) fp16 {phi0,phi1,phi2,vx,vy,vz}
// per (node,f). Gather reads 12 B/lane-edge instead of 24 — FETCH_SIZE
// (the proven-invariant bottleneck, 455 MB across R0-R9) halves.
// ---------------------------------------------------------------------------
__global__ __launch_bounds__(256) void work_kernel(
    const float* __restrict__ d_ij, const float* __restrict__ unit_r,
    const int* __restrict__ nbrs, const float* __restrict__ v_i,
    int* __restrict__ cnt, float* __restrict__ pack,
    const float* __restrict__ h,
    const __bf16* __restrict__ W1T, const float* __restrict__ b1,
    const __bf16* __restrict__ W2T, const float* __restrict__ b2,
    _Float16* __restrict__ gh, int E, int EB, int MB, int N)
{
    __shared__ __bf16 t_lds[16 * TLDS_STRIDE];   // mlp only; 4.3 KB

    const int tid = threadIdx.x;
    const int b   = blockIdx.x;

    if (b < EB) {                       // ---- build
        const int e = b * 256 + tid;
        if (e >= E) return;
        const int2 nb = ((const int2*)nbrs)[e];
        const int dst = nb.x;
        const int src = nb.y;
        const int slot = atomicAdd(&cnt[dst], 1);
        if (slot >= CAP) return;

        const float d = d_ij[e];
        const float x = (float)M_PI * d * (1.0f / CUTOFF);
        float sx, cx;
        __sincosf(x, &sx, &cx);
        const float fcut = (d < CUTOFF) ? 0.5f * (cx + 1.0f) : 0.0f;
        float4 q0, q1;
        q0.x = sx * fcut / d;           // rbff_1; recurrence keeps fcut/d scale
        q0.y = 2.0f * cx;
        q0.z = fcut;
        q0.w = unit_r[3 * e + 0];
        q1.x = unit_r[3 * e + 1];
        q1.y = unit_r[3 * e + 2];
        q1.z = __int_as_float(src);
        q1.w = 0.0f;
        float4* pk = (float4*)(pack + ((size_t)dst * CAP + slot) * 8);
        pk[0] = q0;
        pk[1] = q1;
        return;
    }

    if (b >= EB + MB) {                 // ---- vcast: v_i fp32 -> fp16 record
        const int idx = (b - EB - MB) * 256 + tid;   // (node*128 + f)
        if (idx >= N * F) return;
        const int node = idx >> 7, f = idx & 127;
        const float* vs = v_i + (size_t)node * THREEF + 3 * f;
        _Float16* gp = gh + (size_t)node * 768 + 6 * f + 3;
        gp[0] = (_Float16)vs[0];
        gp[1] = (_Float16)vs[1];
        gp[2] = (_Float16)vs[2];
        return;
    }

    // ---- mlp
    const int wave = tid >> 6;
    const int lane = tid & 63;
    const int m    = lane & 15;
    const int quad = lane >> 4;
    const int node0 = (b - EB) * 16;
    if (node0 >= N) return;

    bf16x8 a1[4];
    #pragma unroll
    for (int kb = 0; kb < 4; ++kb) {
        const float* hp = h + (size_t)(node0 + m) * F + kb * 32 + quad * 8;
        const float4 x0 = *(const float4*)hp;
        const float4 x1 = *(const float4*)(hp + 4);
        bf16x8 a;
        a[0] = (__bf16)x0.x; a[1] = (__bf16)x0.y;
        a[2] = (__bf16)x0.z; a[3] = (__bf16)x0.w;
        a[4] = (__bf16)x1.x; a[5] = (__bf16)x1.y;
        a[6] = (__bf16)x1.z; a[7] = (__bf16)x1.w;
        a1[kb] = a;
    }

    // W1 + silu: 8 ct tiles, 2 per wave, into shared t
    #pragma unroll
    for (int c2 = 0; c2 < 2; ++c2) {
        const int ct = wave * 2 + c2;
        f32x4 acc = {0.0f, 0.0f, 0.0f, 0.0f};
        #pragma unroll
        for (int kb = 0; kb < 4; ++kb) {
            const bf16x8 bb =
                *(const bf16x8*)(W1T + (size_t)(ct * 16 + m) * F + kb * 32 + quad * 8);
            acc = __builtin_amdgcn_mfma_f32_16x16x32_bf16(a1[kb], bb, acc, 0, 0, 0);
        }
        const int col = ct * 16 + m;
        const float bb = b1[col];
        #pragma unroll
        for (int reg = 0; reg < 4; ++reg) {
            const float x = acc[reg] + bb;
            const float s = x / (1.0f + __expf(-x));
            t_lds[(quad * 4 + reg) * TLDS_STRIDE + col] = (__bf16)s;
        }
    }
    __syncthreads();

    bf16x8 a2[4];
    #pragma unroll
    for (int kb = 0; kb < 4; ++kb)
        a2[kb] = *(const bf16x8*)&t_lds[m * TLDS_STRIDE + kb * 32 + quad * 8];

    // W2: 24 ct tiles, 6 per wave; phi written fp16 into the combined record
    #pragma unroll
    for (int c6 = 0; c6 < 6; ++c6) {
        const int ct = c6 * 4 + wave;
        f32x4 acc = {0.0f, 0.0f, 0.0f, 0.0f};
        #pragma unroll
        for (int kb = 0; kb < 4; ++kb) {
            const bf16x8 bb =
                *(const bf16x8*)(W2T + (size_t)(ct * 16 + m) * F + kb * 32 + quad * 8);
            acc = __builtin_amdgcn_mfma_f32_16x16x32_bf16(a2[kb], bb, acc, 0, 0, 0);
        }
        const int col   = ct * 16 + m;
        const int plane = col >> 7;
        const int fc    = col & 127;
        const float bb  = b2[col];
        #pragma unroll
        for (int reg = 0; reg < 4; ++reg) {
            const int row = quad * 4 + reg;
            gh[(size_t)(node0 + row) * 768 + 6 * fc + plane] =
                (_Float16)(acc[reg] + bb);
        }
    }
}

// ---------------------------------------------------------------------------
// Gather: 256 threads = 2 nodes/block. R9 structure kept (4-edge blocking,
// 84 VGPR no-spill via amdgpu_waves_per_eu(2,4), packed Chebyshev, SALU
// gather addresses). R10 delta: phi+v gathered from the combined fp16
// record — 3 dword loads (12 B/lane-edge) instead of 6 dwords (24 B).
// R0-R9 proved dur tracks FETCH_SIZE only (invariant 455 MB while VALU
// -45%, L1 bytes /3, occ 27-45% all left dur at ~143-146 us).
// ---------------------------------------------------------------------------
__global__ __launch_bounds__(256)
__attribute__((amdgpu_waves_per_eu(2, 4)))
void gather_kernel(
    const _Float16* __restrict__ gh,     // (N,128,6) {phi0,phi1,phi2,vx,vy,vz}
    const float* __restrict__ WrT,       // (5,3,128,4) chunked transpose
    const float* __restrict__ br,        // (384)
    const int*   __restrict__ cnt,       // (N)
    const float* __restrict__ pack,      // (N,CAP,8)
    float* __restrict__ dh,              // (N,128)
    float* __restrict__ dv,              // (N,128,3)
    int N)
{
    __shared__ float4 s_pack[2][CAP * 2];   // 4 KB

    const int tid  = threadIdx.x;
    const int half = tid >> 7;
    const int f    = tid & 127;
    const int node = blockIdx.x * 2 + half;

    const int deg0 = cnt[node];
    const int deg  = deg0 < CAP ? deg0 : CAP;
    const int degR = (deg + 3) & ~3;         // pad to 4-edge blocks (<= CAP)

    {   // stage this node's pack rows; zero the pad slots
        const float4* srcp = (const float4*)(pack + (size_t)node * CAP * 8);
        if (f < 2 * degR) {
            float4 v = make_float4(0.0f, 0.0f, 0.0f, 0.0f);
            if (f < 2 * deg) v = srcp[f];
            s_pack[half][f] = v;
        }
    }
    __syncthreads();

    const float br0 = br[f], br1 = br[f + 128], br2 = br[f + 256];
    const f32x4* wT = (const f32x4*)WrT;   // wT[(n4*3 + c)*128 + f]

    float dh_acc = 0.0f, dvx = 0.0f, dvy = 0.0f, dvz = 0.0f;

    for (int i0 = 0; i0 < degR; i0 += 4) {
        // ---- prologue: per-edge seeds + issue all gather loads (SALU addr)
        float s1[4], twoc[4], fcut[4], ux[4], uy[4], uz[4];
        float ph0[4], ph1[4], ph2[4], vx[4], vy[4], vz[4];
        #pragma unroll
        for (int j = 0; j < 4; ++j) {
            const float4 q0 = s_pack[half][2 * (i0 + j)];
            const float4 q1 = s_pack[half][2 * (i0 + j) + 1];
            s1[j] = q0.x; twoc[j] = q0.y; fcut[j] = q0.z;
            ux[j] = q0.w; uy[j] = q1.x;   uz[j] = q1.y;
            const int src = __builtin_amdgcn_readfirstlane(__float_as_int(q1.z));
            const unsigned int* gb =
                (const unsigned int*)(gh + (size_t)src * 768) + 3 * f;
            const unsigned int d0 = gb[0], d1 = gb[1], d2 = gb[2];
            ph0[j] = loh(d0); ph1[j] = hih(d0);
            ph2[j] = loh(d1); vx[j]  = hih(d1);
            vy[j]  = loh(d2); vz[j]  = hih(d2);
        }

        // ---- contraction state: packed Chebyshev double-step (R8-verified)
        f32x2 t2[4], rc[4], rp[4], A0[4], A1[4], A2[4];
        #pragma unroll
        for (int j = 0; j < 4; ++j) {
            const float t2s = fmaf(twoc[j], twoc[j], -2.0f);
            t2[j][0] = t2s;      t2[j][1] = t2s;
            rc[j][0] = s1[j];    rc[j][1] = twoc[j] * s1[j];   // (r1, r2)
            rp[j][0] = -s1[j];   rp[j][1] = 0.0f;              // (r-1, r0)
            A0[j] = (f32x2){0.0f, 0.0f};
            A1[j] = (f32x2){0.0f, 0.0f};
            A2[j] = (f32x2){0.0f, 0.0f};
        }

        #pragma unroll
        for (int n4 = 0; n4 < 5; ++n4) {
            const f32x4 w0 = wT[(n4 * 3 + 0) * 128 + f];
            const f32x4 w1 = wT[(n4 * 3 + 1) * 128 + f];
            const f32x4 w2 = wT[(n4 * 3 + 2) * 128 + f];
            const f32x2 w0lo = __builtin_shufflevector(w0, w0, 0, 1);
            const f32x2 w1lo = __builtin_shufflevector(w1, w1, 0, 1);
            const f32x2 w2lo = __builtin_shufflevector(w2, w2, 0, 1);
            const f32x2 w0hi = __builtin_shufflevector(w0, w0, 2, 3);
            const f32x2 w1hi = __builtin_shufflevector(w1, w1, 2, 3);
            const f32x2 w2hi = __builtin_shufflevector(w2, w2, 2, 3);
            #pragma unroll
            for (int j = 0; j < 4; ++j) {
                A0[j] = __builtin_elementwise_fma(rc[j], w0lo, A0[j]);
                A1[j] = __builtin_elementwise_fma(rc[j], w1lo, A1[j]);
                A2[j] = __builtin_elementwise_fma(rc[j], w2lo, A2[j]);
                f32x2 rn = __builtin_elementwise_fma(t2[j], rc[j], -rp[j]);
                rp[j] = rc[j]; rc[j] = rn;
                A0[j] = __builtin_elementwise_fma(rc[j], w0hi, A0[j]);
                A1[j] = __builtin_elementwise_fma(rc[j], w1hi, A1[j]);
                A2[j] = __builtin_elementwise_fma(rc[j], w2hi, A2[j]);
                rn = __builtin_elementwise_fma(t2[j], rc[j], -rp[j]);
                rp[j] = rc[j]; rc[j] = rn;
            }
        }

        // ---- epilogue
        #pragma unroll
        for (int j = 0; j < 4; ++j) {
            const float a0 = fmaf(br0, fcut[j], A0[j][0] + A0[j][1]);
            const float a1 = fmaf(br1, fcut[j], A1[j][0] + A1[j][1]);
            const float a2 = fmaf(br2, fcut[j], A2[j][0] + A2[j][1]);
            const float f1 = ph0[j] * a0;
            const float f2 = ph1[j] * a1;
            const float f3 = ph2[j] * a2;
            dh_acc += f3;
            dvx = fmaf(f1, ux[j], fmaf(f2, vx[j], dvx));
            dvy = fmaf(f1, uy[j], fmaf(f2, vy[j], dvy));
            dvz = fmaf(f1, uz[j], fmaf(f2, vz[j], dvz));
        }
    }

    dh[(size_t)node * F + f] = dh_acc;
    float* dvp = dv + (size_t)node * THREEF + 3 * f;
    dvp[0] = dvx;
    dvp[1] = dvy;
    dvp[2] = dvz;
}

extern "C" void kernel_launch(void* const* d_in, const int* in_sizes, int n_in,
                              void* d_out, int out_size, void* d_ws, size_t ws_size,
                              hipStream_t stream) {
    const float* h_i    = (const float*)d_in[0];
    const float* v_i    = (const float*)d_in[1];
    const float* d_ij   = (const float*)d_in[2];
    const float* unit_r = (const float*)d_in[3];
    const int*   nbrs   = (const int*)  d_in[4];
    const float* W1     = (const float*)d_in[5];
    const float* b1     = (const float*)d_in[6];
    const float* W2     = (const float*)d_in[7];
    const float* b2     = (const float*)d_in[8];
    const float* Wr     = (const float*)d_in[9];
    const float* br     = (const float*)d_in[10];

    const int N = in_sizes[0] / F;       // 20000
    const int E = in_sizes[2];           // 320000

    float* dh = (float*)d_out;              // (N,128)
    float* dv = dh + (size_t)N * F;         // (N,128,3)

    // workspace: gh (N*768 fp16 = N*384 float-equiv) | pack | WrT | cnt | W1T | W2T
    _Float16* gh  = (_Float16*)d_ws;                       // 30.7 MB
    float*  pack = (float*)d_ws + (size_t)3 * N * F / 2 + N * F / 2; // after N*384 floats
    // (N*768 halves == N*384 floats)
    pack = (float*)((char*)d_ws + (size_t)N * 768 * sizeof(_Float16));
    float*  WrT  = pack + (size_t)N * CAP * 8;             // 30 KB
    int*    cnt  = (int*)(WrT + 5 * 3 * 128 * 4);          // 80 KB
    __bf16* W1T  = (__bf16*)(cnt + N);                     // 32 KB
    __bf16* W2T  = W1T + 128 * 128;                        // 96 KB

    const int EB = (E + 255) / 256;      // 1250 build blocks
    const int MB = (N + 15) / 16;        // 1250 mlp blocks
    const int VB = (N * F + 255) / 256;  // 10000 vcast blocks
    const int ZB = ((N + 3) / 4 + 255) / 256;   // cnt-zero blocks (20)

    init_kernel<<<256 + 8 + ZB, 256, 0, stream>>>(W1, W2, Wr, W1T, W2T, WrT,
                                                  cnt, N);
    work_kernel<<<EB + MB + VB, 256, 0, stream>>>(d_ij, unit_r, nbrs, v_i,
                                                  cnt, pack, h_i, W1T, b1,
                                                  W2T, b2, gh, E, EB, MB, N);
    gather_kernel<<<N / 2, 256, 0, stream>>>(gh, WrT, br, cnt, pack,
                                             dh, dv, N);
}